// Round 3
// baseline (297.124 us; speedup 1.0000x reference)
//
#include <hip/hip_runtime.h>
#include <math.h>

#define AGENT __HIP_MEMORY_SCOPE_AGENT

// QLSTM: 12-qubit statevector sim, 16 timesteps x 4 gates x 64 samples,
// fully fused into one kernel. Qubit q <-> bit (11-q) of the amp index.
// LDS: ping-pong float2 buffers, swizzle p = i ^ ((i>>4)&15) (even 4/bank-pair
// spread on all pass patterns and both sigma gathers, by GF(2) rank check).

__device__ __forceinline__ int swz(int i) { return i ^ ((i >> 4) & 15); }

// CNOT ring layer 0 (r=1) composite perm: new[i] = old[sigma0(i)].
__device__ __forceinline__ int sigma0(int w) {
    int r = w ^ (w >> 1);
    r ^= (w & 1) ? 0xC00 : 0;
    return r;
}
// CNOT ring layer 1 (r=2).
__device__ __forceinline__ int sigma1(int w) {
    int r = w ^ (w >> 2);
    r ^= (w & 2) ? 0xA00 : 0;
    r ^= (w & 1) ? 0x500 : 0;
    return r;
}

__device__ __forceinline__ float ftanh(float x) {
    x = fminf(fmaxf(x, -15.f), 15.f);
    const float e = __expf(2.f * x);
    return (e - 1.f) / (e + 1.f);
}
__device__ __forceinline__ float fsigm(float x) { return 1.f / (1.f + __expf(-x)); }

// Apply 4 Rot gates (strides 8,4,2,1 in j) to 16 register-resident amps.
__device__ __forceinline__ void rot4(float ar[16], float ai[16],
                                     const float* __restrict__ m4) {
#pragma unroll
    for (int k = 0; k < 4; ++k) {
        const float g0r = m4[k*8+0], g0i = m4[k*8+1];
        const float g1r = m4[k*8+2], g1i = m4[k*8+3];
        const float g2r = m4[k*8+4], g2i = m4[k*8+5];
        const float g3r = m4[k*8+6], g3i = m4[k*8+7];
        const int vs = 8 >> k;
#pragma unroll
        for (int p = 0; p < 8; ++p) {
            const int lowm = vs - 1;
            const int j0 = ((p & ~lowm) << 1) | (p & lowm);
            const int j1 = j0 | vs;
            const float a0r = ar[j0], a0i = ai[j0];
            const float a1r = ar[j1], a1i = ai[j1];
            ar[j0] = g0r*a0r - g0i*a0i + g1r*a1r - g1i*a1i;
            ai[j0] = g0r*a0i + g0i*a0r + g1r*a1i + g1i*a1r;
            ar[j1] = g2r*a0r - g2i*a0i + g3r*a1r - g3i*a1i;
            ai[j1] = g2r*a0i + g2i*a0r + g3r*a1i + g3i*a1r;
        }
    }
}

__global__ __launch_bounds__(256, 1)
void qlstm_fused(const float* __restrict__ inputs,
                 const float* __restrict__ wf, const float* __restrict__ wi,
                 const float* __restrict__ wu, const float* __restrict__ wo,
                 const float* __restrict__ fW, const float* __restrict__ fb,
                 const float* __restrict__ iW, const float* __restrict__ ib,
                 const float* __restrict__ uW, const float* __restrict__ ub,
                 const float* __restrict__ oW, const float* __restrict__ ob,
                 float* __restrict__ gact,      // ws: [2][4][64][4]
                 unsigned* __restrict__ ctr,    // ws: [16][64], memset 0
                 float* __restrict__ out)       // 4096 + 256 + 256
{
    __shared__ float2 buf0[4096], buf1[4096];
    __shared__ float rotm[24 * 8];
    __shared__ float rxc[12], rxs[12];
    __shared__ float zredw[4 * 12];

    const int tid = threadIdx.x;
    const int b = blockIdx.x & 63;
    const int g = blockIdx.x >> 6;

    const float* wsel = (g == 0) ? wf : (g == 1) ? wi : (g == 2) ? wu : wo;
    const float* Wsel = (g == 0) ? fW : (g == 1) ? iW : (g == 2) ? uW : oW;
    const float* bsel = (g == 0) ? fb : (g == 1) ? ib : (g == 2) ? ub : ob;

    // Rot matrices are timestep-invariant: compute once.
    if (tid >= 64 && tid < 88) {
        const int k = tid - 64;                  // l*12 + qubit
        const float phi = wsel[k*3+0], th = wsel[k*3+1], om = wsel[k*3+2];
        float ct, sth; __sincosf(0.5f * th, &sth, &ct);
        float ca, sa;  __sincosf(0.5f * (phi + om), &sa, &ca);
        float cb, sb;  __sincosf(0.5f * (phi - om), &sb, &cb);
        float* m = rotm + k * 8;
        m[0] =  ca * ct;  m[1] = -sa * ct;
        m[2] = -cb * sth; m[3] = -sb * sth;
        m[4] =  cb * sth; m[5] = -sb * sth;
        m[6] =  ca * ct;  m[7] =  sa * ct;
    }

    float c_ = 0.f, h_ = 0.f;                    // live in threads 0..3
    const int aBase = tid << 4, aMsk = tid & 15;
    const int bBase = ((tid >> 4) << 8) | (tid & 15);
    const int cBase = tid ^ ((tid >> 4) & 15);

    for (int t = 0; t < 16; ++t) {
        // ---- group rendezvous on step t-1, then h/RX setup ----
        if (t > 0) {
            if (tid == 0) {
                while (__hip_atomic_load(&ctr[(t - 1) * 64 + b],
                                         __ATOMIC_ACQUIRE, AGENT) < 16u)
                    __builtin_amdgcn_s_sleep(1);
            }
            __syncthreads();
            if (tid < 4) {
                float* ga = gact + ((t - 1) & 1) * 1024 + b * 4 + tid;
                const float f_ = __hip_atomic_load(ga + 0,   __ATOMIC_RELAXED, AGENT);
                const float i_ = __hip_atomic_load(ga + 256, __ATOMIC_RELAXED, AGENT);
                const float u_ = __hip_atomic_load(ga + 512, __ATOMIC_RELAXED, AGENT);
                const float o_ = __hip_atomic_load(ga + 768, __ATOMIC_RELAXED, AGENT);
                c_ = f_ * c_ + i_ * u_;
                h_ = o_ * ftanh(c_);
                if (g == 0) out[(t - 1) * 256 + b * 4 + tid] = h_;
                __sincosf(0.5f * h_, &rxs[8 + tid], &rxc[8 + tid]);
            }
        } else {
            if (tid < 4) { rxs[8 + tid] = 0.f; rxc[8 + tid] = 1.f; }
        }
        if (tid >= 96 && tid < 104) {
            const int q = tid - 96;
            __sincosf(0.5f * inputs[t * 512 + b * 8 + q], &rxs[q], &rxc[q]);
        }
        __syncthreads();

        float ar[16], ai[16];

        // ---- A0: post-RX product state + Rot L0 q8..11 -> buf0 (own slice) ----
        {
            float rb = 1.f; int kb = 0;
#pragma unroll
            for (int q = 0; q < 8; ++q) {
                const int bit = (tid >> (7 - q)) & 1;
                rb *= bit ? rxs[q] : rxc[q];
                kb += bit;
            }
#pragma unroll
            for (int j = 0; j < 16; ++j) {
                float r = rb;
                r *= (j & 8) ? rxs[8]  : rxc[8];
                r *= (j & 4) ? rxs[9]  : rxc[9];
                r *= (j & 2) ? rxs[10] : rxc[10];
                r *= (j & 1) ? rxs[11] : rxc[11];
                const int k = (kb + __popc(j)) & 3;   // phase (-i)^k
                ar[j] = (k == 0) ? r : (k == 2) ? -r : 0.f;
                ai[j] = (k == 1) ? -r : (k == 3) ? r : 0.f;
            }
            rot4(ar, ai, rotm + 64);
#pragma unroll
            for (int j = 0; j < 16; ++j)
                buf0[aBase | (j ^ aMsk)] = make_float2(ar[j], ai[j]);
        }
        __builtin_amdgcn_wave_barrier();   // wave-local: no __syncthreads needed

        // ---- B0: Rot L0 q4..7, wave-local quarter of buf0, in place ----
        {
#pragma unroll
            for (int j = 0; j < 16; ++j) {
                const float2 v = buf0[bBase ^ (j << 4) ^ j];
                ar[j] = v.x; ai[j] = v.y;
            }
            rot4(ar, ai, rotm + 32);
#pragma unroll
            for (int j = 0; j < 16; ++j)
                buf0[bBase ^ (j << 4) ^ j] = make_float2(ar[j], ai[j]);
        }
        __syncthreads();                   // b1: C0 reads cross-wave

        // ---- C0: Rot L0 q0..3 (stride 256), in place in buf0 ----
        {
#pragma unroll
            for (int j = 0; j < 16; ++j) {
                const float2 v = buf0[cBase + (j << 8)];
                ar[j] = v.x; ai[j] = v.y;
            }
            rot4(ar, ai, rotm + 0);
#pragma unroll
            for (int j = 0; j < 16; ++j)
                buf0[cBase + (j << 8)] = make_float2(ar[j], ai[j]);
        }
        __syncthreads();                   // b2: sigma0 gather reads everything

        // ---- A1: gather sigma0 from buf0 + Rot L1 q8..11 -> buf1 (own slice) ----
        {
#pragma unroll
            for (int j = 0; j < 16; ++j) {
                const float2 v = buf0[swz(sigma0(aBase + j))];
                ar[j] = v.x; ai[j] = v.y;
            }
            rot4(ar, ai, rotm + 160);
#pragma unroll
            for (int j = 0; j < 16; ++j)
                buf1[aBase | (j ^ aMsk)] = make_float2(ar[j], ai[j]);
        }
        __builtin_amdgcn_wave_barrier();   // wave-local again

        // ---- B1: Rot L1 q4..7, wave-local quarter of buf1 ----
        {
#pragma unroll
            for (int j = 0; j < 16; ++j) {
                const float2 v = buf1[bBase ^ (j << 4) ^ j];
                ar[j] = v.x; ai[j] = v.y;
            }
            rot4(ar, ai, rotm + 128);
#pragma unroll
            for (int j = 0; j < 16; ++j)
                buf1[bBase ^ (j << 4) ^ j] = make_float2(ar[j], ai[j]);
        }
        __syncthreads();                   // b3: C1 reads cross-wave

        // ---- C1: Rot L1 q0..3, in place in buf1 ----
        {
#pragma unroll
            for (int j = 0; j < 16; ++j) {
                const float2 v = buf1[cBase + (j << 8)];
                ar[j] = v.x; ai[j] = v.y;
            }
            rot4(ar, ai, rotm + 96);
#pragma unroll
            for (int j = 0; j < 16; ++j)
                buf1[cBase + (j << 8)] = make_float2(ar[j], ai[j]);
        }
        __syncthreads();                   // b4: sigma1 gather reads everything

        // ---- Expvals: CNOT ring L1 fused as gather sigma1 from buf1 ----
        float S = 0.f, z8 = 0.f, z9 = 0.f, z10 = 0.f, z11 = 0.f;
#pragma unroll
        for (int j = 0; j < 16; ++j) {
            const float2 v = buf1[swz(sigma1(aBase + j))];
            const float p = v.x * v.x + v.y * v.y;
            S += p;
            z8  += (j & 8) ? -p : p;
            z9  += (j & 4) ? -p : p;
            z10 += (j & 2) ? -p : p;
            z11 += (j & 1) ? -p : p;
        }
        float zq[12];
#pragma unroll
        for (int q = 0; q < 8; ++q)
            zq[q] = ((tid >> (7 - q)) & 1) ? -S : S;
        zq[8] = z8; zq[9] = z9; zq[10] = z10; zq[11] = z11;

        const int lane = tid & 63, wv = tid >> 6;
#pragma unroll
        for (int q = 0; q < 12; ++q) {
            float v = zq[q];
#pragma unroll
            for (int off = 32; off > 0; off >>= 1) v += __shfl_down(v, off);
            if (lane == 0) zredw[wv * 12 + q] = v;
        }
        __syncthreads();                   // b5

        // ---- Linear head + activation -> gact; release-add rendezvous ----
        if (tid < 4) {
            float acc = bsel[tid];
#pragma unroll
            for (int q = 0; q < 12; ++q) {
                const float zs = zredw[q] + zredw[12 + q] + zredw[24 + q] + zredw[36 + q];
                acc += Wsel[tid * 12 + q] * zs;
            }
            const float act = (g == 2) ? ftanh(acc) : fsigm(acc);
            __hip_atomic_store(&gact[(t & 1) * 1024 + g * 256 + b * 4 + tid], act,
                               __ATOMIC_RELAXED, AGENT);
            __hip_atomic_fetch_add(&ctr[t * 64 + b], 1u, __ATOMIC_RELEASE, AGENT);
        }
        // no barrier here: next iteration's rendezvous + __syncthreads covers it
    }

    // ---- Finalize: consume step-15 activations ----
    if (tid == 0) {
        while (__hip_atomic_load(&ctr[15 * 64 + b], __ATOMIC_ACQUIRE, AGENT) < 16u)
            __builtin_amdgcn_s_sleep(1);
    }
    __syncthreads();
    if (g == 0 && tid < 4) {
        float* ga = gact + 1024 + b * 4 + tid;          // slot 15&1 = 1
        const float f_ = __hip_atomic_load(ga + 0,   __ATOMIC_RELAXED, AGENT);
        const float i_ = __hip_atomic_load(ga + 256, __ATOMIC_RELAXED, AGENT);
        const float u_ = __hip_atomic_load(ga + 512, __ATOMIC_RELAXED, AGENT);
        const float o_ = __hip_atomic_load(ga + 768, __ATOMIC_RELAXED, AGENT);
        c_ = f_ * c_ + i_ * u_;
        h_ = o_ * ftanh(c_);
        out[3840 + b * 4 + tid] = h_;   // outputs[15]
        out[4096 + b * 4 + tid] = h_;   // hx
        out[4352 + b * 4 + tid] = c_;   // cx
    }
}

extern "C" void kernel_launch(void* const* d_in, const int* in_sizes, int n_in,
                              void* d_out, int out_size, void* d_ws, size_t ws_size,
                              hipStream_t stream) {
    (void)in_sizes; (void)n_in; (void)out_size; (void)ws_size;
    const float* inputs = (const float*)d_in[0];
    const float* wf = (const float*)d_in[1];
    const float* wi = (const float*)d_in[2];
    const float* wu = (const float*)d_in[3];
    const float* wo = (const float*)d_in[4];
    const float* fW = (const float*)d_in[5];
    const float* fb = (const float*)d_in[6];
    const float* iW = (const float*)d_in[7];
    const float* ib = (const float*)d_in[8];
    const float* uW = (const float*)d_in[9];
    const float* ub = (const float*)d_in[10];
    const float* oW = (const float*)d_in[11];
    const float* ob = (const float*)d_in[12];
    float* out = (float*)d_out;
    unsigned* ctr = (unsigned*)d_ws;                 // [16][64] uints
    float* gact = (float*)d_ws + 1024;               // [2][4][64][4] floats

    hipMemsetAsync(ctr, 0, 1024 * sizeof(unsigned), stream);

    void* args[] = { (void*)&inputs, (void*)&wf, (void*)&wi, (void*)&wu, (void*)&wo,
                     (void*)&fW, (void*)&fb, (void*)&iW, (void*)&ib,
                     (void*)&uW, (void*)&ub, (void*)&oW, (void*)&ob,
                     (void*)&gact, (void*)&ctr, (void*)&out };
    hipError_t err = hipLaunchCooperativeKernel((const void*)qlstm_fused,
                                                dim3(256), dim3(256),
                                                args, 0, stream);
    if (err != hipSuccess) {
        // Fallback: plain launch. 256 WGs (1/CU, 66KB LDS) are co-resident on
        // an otherwise-idle 256-CU device, so the group rendezvous still works.
        qlstm_fused<<<dim3(256), dim3(256), 0, stream>>>(
            inputs, wf, wi, wu, wo, fW, fb, iW, ib, uW, ub, oW, ob,
            gact, ctr, out);
    }
}

// Round 4
// 245.021 us; speedup vs baseline: 1.2127x; 1.2127x over previous
//
#include <hip/hip_runtime.h>
#include <math.h>

#define AGENT __HIP_MEMORY_SCOPE_AGENT

// QLSTM: 12-qubit statevector sim, 16 steps x 4 gates x 64 samples, one fused
// kernel. Qubit q <-> bit (11-q) of the flat amp index. Pre-CNOT state
// factorizes as U(q0..7, x_t-only) (x) V(q8..11, h-only): U is simulated on
// wave 0 BEFORE the h rendezvous (hides spin latency), V is built per-thread.
// LDS swizzle p = i ^ ((i>>4)&15) as r3 (conflict profile verified).

__device__ __forceinline__ int swz(int i) { return i ^ ((i >> 4) & 15); }

// CNOT ring layer 0 (r=1) composite perm: new[i] = old[sigma0(i)].
__device__ __forceinline__ int sigma0(int w) {
    int r = w ^ (w >> 1);
    r ^= (w & 1) ? 0xC00 : 0;
    return r;
}
// CNOT ring layer 1 (r=2).
__device__ __forceinline__ int sigma1(int w) {
    int r = w ^ (w >> 2);
    r ^= (w & 2) ? 0xA00 : 0;
    r ^= (w & 1) ? 0x500 : 0;
    return r;
}

__device__ __forceinline__ float ftanh(float x) {
    x = fminf(fmaxf(x, -15.f), 15.f);
    const float e = __expf(2.f * x);
    return (e - 1.f) / (e + 1.f);
}
__device__ __forceinline__ float fsigm(float x) { return 1.f / (1.f + __expf(-x)); }

// Apply 4 Rot gates (strides 8,4,2,1 in j) to 16 register-resident amps.
__device__ __forceinline__ void rot4(float ar[16], float ai[16],
                                     const float* __restrict__ m4) {
#pragma unroll
    for (int k = 0; k < 4; ++k) {
        const float g0r = m4[k*8+0], g0i = m4[k*8+1];
        const float g1r = m4[k*8+2], g1i = m4[k*8+3];
        const float g2r = m4[k*8+4], g2i = m4[k*8+5];
        const float g3r = m4[k*8+6], g3i = m4[k*8+7];
        const int vs = 8 >> k;
#pragma unroll
        for (int p = 0; p < 8; ++p) {
            const int lowm = vs - 1;
            const int j0 = ((p & ~lowm) << 1) | (p & lowm);
            const int j1 = j0 | vs;
            const float a0r = ar[j0], a0i = ai[j0];
            const float a1r = ar[j1], a1i = ai[j1];
            ar[j0] = g0r*a0r - g0i*a0i + g1r*a1r - g1i*a1i;
            ai[j0] = g0r*a0i + g0i*a0r + g1r*a1i + g1i*a1r;
            ar[j1] = g2r*a0r - g2i*a0i + g3r*a1r - g3i*a1i;
            ai[j1] = g2r*a0i + g2i*a0r + g3r*a1i + g3i*a1r;
        }
    }
}

__global__ __launch_bounds__(256, 1)
void qlstm_fused(const float* __restrict__ inputs,
                 const float* __restrict__ wf, const float* __restrict__ wi,
                 const float* __restrict__ wu, const float* __restrict__ wo,
                 const float* __restrict__ fW, const float* __restrict__ fb,
                 const float* __restrict__ iW, const float* __restrict__ ib,
                 const float* __restrict__ uW, const float* __restrict__ ub,
                 const float* __restrict__ oW, const float* __restrict__ ob,
                 float* __restrict__ gact,      // ws: [2][4][64][4]
                 unsigned* __restrict__ ctr,    // ws: [64][16], memset 0
                 float* __restrict__ out)       // 4096 + 256 + 256
{
    __shared__ float2 buf0[4096], buf1[4096];
    __shared__ float2 Ush[256];
    __shared__ float rotm[24 * 8];
    __shared__ float zredw[4 * 12];

    const int tid = threadIdx.x;
    const int b = blockIdx.x & 63;
    const int g = blockIdx.x >> 6;

    const float* wsel = (g == 0) ? wf : (g == 1) ? wi : (g == 2) ? wu : wo;
    const float* Wsel = (g == 0) ? fW : (g == 1) ? iW : (g == 2) ? uW : oW;
    const float* bsel = (g == 0) ? fb : (g == 1) ? ib : (g == 2) ? ub : ob;

    // Rot matrices are timestep-invariant: compute once (wave 1).
    if (tid >= 64 && tid < 88) {
        const int k = tid - 64;                  // l*12 + qubit
        const float phi = wsel[k*3+0], th = wsel[k*3+1], om = wsel[k*3+2];
        float ct, sth; __sincosf(0.5f * th, &sth, &ct);
        float ca, sa;  __sincosf(0.5f * (phi + om), &sa, &ca);
        float cb, sb;  __sincosf(0.5f * (phi - om), &sb, &cb);
        float* m = rotm + k * 8;
        m[0] =  ca * ct;  m[1] = -sa * ct;
        m[2] = -cb * sth; m[3] = -sb * sth;
        m[4] =  cb * sth; m[5] = -sb * sth;
        m[6] =  ca * ct;  m[7] =  sa * ct;
    }
    __syncthreads();

    float c4[4] = {0.f, 0.f, 0.f, 0.f};
    float h4[4] = {0.f, 0.f, 0.f, 0.f};
    const int aBase = tid << 4, aMsk = tid & 15;
    const int bBase = ((tid >> 4) << 8) | (tid & 15);
    const int cBase = tid ^ ((tid >> 4) & 15);

    for (int t = 0; t < 16; ++t) {
        // ==== phase 1 (pre-h): wave0 simulates U(q0..7); tid64 spins ====
        if (tid < 64) {
            // idx8 = k*64 + lane; qubit0<->k bit1, qubit1<->k bit0,
            // qubits 2..7 <-> lane bits 5..0.
            float cq[8], sq[8];
#pragma unroll
            for (int q = 0; q < 8; ++q)
                __sincosf(0.5f * inputs[t * 512 + b * 8 + q], &sq[q], &cq[q]);
            float lr = 1.f; int lkb = 0;
#pragma unroll
            for (int q = 2; q < 8; ++q) {
                const int bit = (tid >> (7 - q)) & 1;
                lr *= bit ? sq[q] : cq[q];
                lkb += bit;
            }
            float ur[4], ui[4];
#pragma unroll
            for (int k = 0; k < 4; ++k) {
                const int b0 = (k >> 1) & 1, b1 = k & 1;
                const float r = lr * (b0 ? sq[0] : cq[0]) * (b1 ? sq[1] : cq[1]);
                const int kb = (lkb + b0 + b1) & 3;      // phase (-i)^kb
                ur[k] = (kb == 0) ? r : (kb == 2) ? -r : 0.f;
                ui[k] = (kb == 1) ? -r : (kb == 3) ? r : 0.f;
            }
            // Rot L0 qubit0 (k-pairs stride 2) and qubit1 (stride 1), local.
            {
                const float* m = rotm;               // qubit 0
#pragma unroll
                for (int k = 0; k < 2; ++k) {
                    const float a0r = ur[k], a0i = ui[k];
                    const float a1r = ur[k+2], a1i = ui[k+2];
                    ur[k]   = m[0]*a0r - m[1]*a0i + m[2]*a1r - m[3]*a1i;
                    ui[k]   = m[0]*a0i + m[1]*a0r + m[2]*a1i + m[3]*a1r;
                    ur[k+2] = m[4]*a0r - m[5]*a0i + m[6]*a1r - m[7]*a1i;
                    ui[k+2] = m[4]*a0i + m[5]*a0r + m[6]*a1i + m[7]*a1r;
                }
                const float* n = rotm + 8;           // qubit 1
#pragma unroll
                for (int k = 0; k < 4; k += 2) {
                    const float a0r = ur[k], a0i = ui[k];
                    const float a1r = ur[k+1], a1i = ui[k+1];
                    ur[k]   = n[0]*a0r - n[1]*a0i + n[2]*a1r - n[3]*a1i;
                    ui[k]   = n[0]*a0i + n[1]*a0r + n[2]*a1i + n[3]*a1r;
                    ur[k+1] = n[4]*a0r - n[5]*a0i + n[6]*a1r - n[7]*a1i;
                    ui[k+1] = n[4]*a0i + n[5]*a0r + n[6]*a1i + n[7]*a1r;
                }
            }
            // Rot L0 qubits 2..7 via shfl_xor.
#pragma unroll
            for (int q = 2; q < 8; ++q) {
                const float* m = rotm + q * 8;
                const int msk = 1 << (7 - q);
                const int bit = (tid >> (7 - q)) & 1;
                const float arr = bit ? m[6] : m[0], ari = bit ? m[7] : m[1];
                const float brr = bit ? m[4] : m[2], bri = bit ? m[5] : m[3];
#pragma unroll
                for (int k = 0; k < 4; ++k) {
                    const float pr = __shfl_xor(ur[k], msk);
                    const float pi = __shfl_xor(ui[k], msk);
                    const float nr = arr*ur[k] - ari*ui[k] + brr*pr - bri*pi;
                    const float ni = arr*ui[k] + ari*ur[k] + brr*pi + bri*pr;
                    ur[k] = nr; ui[k] = ni;
                }
            }
#pragma unroll
            for (int k = 0; k < 4; ++k)
                Ush[k * 64 + tid] = make_float2(ur[k], ui[k]);
        } else if (tid == 64 && t > 0) {
            // relaxed spin (no per-poll invalidate), then one acquire fence
            while (__hip_atomic_load(&ctr[b * 16 + (t - 1)],
                                     __ATOMIC_RELAXED, AGENT) < 4u)
                __builtin_amdgcn_s_sleep(2);
            __threadfence();
        }
        __syncthreads();   // S1: Ush published, h data visible

        // ==== phase 2: every thread tracks all 4 (c,h); build V; outer ====
        float sh[4], ch[4];
        if (t > 0) {
            float* ga = gact + ((t - 1) & 1) * 1024 + b * 4;
#pragma unroll
            for (int u = 0; u < 4; ++u) {
                const float f_ = __hip_atomic_load(ga + u,       __ATOMIC_RELAXED, AGENT);
                const float i_ = __hip_atomic_load(ga + 256 + u, __ATOMIC_RELAXED, AGENT);
                const float g_ = __hip_atomic_load(ga + 512 + u, __ATOMIC_RELAXED, AGENT);
                const float o_ = __hip_atomic_load(ga + 768 + u, __ATOMIC_RELAXED, AGENT);
                c4[u] = f_ * c4[u] + i_ * g_;
                h4[u] = o_ * ftanh(c4[u]);
                __sincosf(0.5f * h4[u], &sh[u], &ch[u]);
            }
            if (g == 0 && tid < 4) out[(t - 1) * 256 + b * 4 + tid] = h4[tid];
        } else {
#pragma unroll
            for (int u = 0; u < 4; ++u) { sh[u] = 0.f; ch[u] = 1.f; }
        }

        float ar[16], ai[16];
        // V(q8..11) = RotL0(q8..11) . RX(h)|0000>, identical on all threads.
#pragma unroll
        for (int j = 0; j < 16; ++j) {
            const float r = ((j & 8) ? sh[0] : ch[0]) * ((j & 4) ? sh[1] : ch[1])
                          * ((j & 2) ? sh[2] : ch[2]) * ((j & 1) ? sh[3] : ch[3]);
            const int k = __popc(j) & 3;
            ar[j] = (k == 0) ? r : (k == 2) ? -r : 0.f;
            ai[j] = (k == 1) ? -r : (k == 3) ? r : 0.f;
        }
        rot4(ar, ai, rotm + 64);                 // L0 q8..11
        {
            const float2 U = Ush[tid];
#pragma unroll
            for (int j = 0; j < 16; ++j)
                buf0[aBase | (j ^ aMsk)] =
                    make_float2(ar[j] * U.x - ai[j] * U.y,
                                ar[j] * U.y + ai[j] * U.x);
        }
        __syncthreads();   // S2: full state in buf0

        // ---- sigma0 gather (CNOT ring L0) + Rot L1 q8..11 -> buf1 ----
#pragma unroll
        for (int j = 0; j < 16; ++j) {
            const float2 v = buf0[swz(sigma0(aBase + j))];
            ar[j] = v.x; ai[j] = v.y;
        }
        rot4(ar, ai, rotm + 160);
#pragma unroll
        for (int j = 0; j < 16; ++j)
            buf1[aBase | (j ^ aMsk)] = make_float2(ar[j], ai[j]);
        __builtin_amdgcn_wave_barrier();         // wave-local buf1 slice

        // ---- B1: Rot L1 q4..7 (wave-local quarter of buf1) ----
#pragma unroll
        for (int j = 0; j < 16; ++j) {
            const float2 v = buf1[bBase ^ (j << 4) ^ j];
            ar[j] = v.x; ai[j] = v.y;
        }
        rot4(ar, ai, rotm + 128);
#pragma unroll
        for (int j = 0; j < 16; ++j)
            buf1[bBase ^ (j << 4) ^ j] = make_float2(ar[j], ai[j]);
        __syncthreads();   // S3: C1 reads cross-wave

        // ---- C1: Rot L1 q0..3 ----
#pragma unroll
        for (int j = 0; j < 16; ++j) {
            const float2 v = buf1[cBase + (j << 8)];
            ar[j] = v.x; ai[j] = v.y;
        }
        rot4(ar, ai, rotm + 96);
#pragma unroll
        for (int j = 0; j < 16; ++j)
            buf1[cBase + (j << 8)] = make_float2(ar[j], ai[j]);
        __syncthreads();   // S4: sigma1 gather reads everything

        // ---- Expvals: CNOT ring L1 fused as gather sigma1 ----
        float S = 0.f, z8 = 0.f, z9 = 0.f, z10 = 0.f, z11 = 0.f;
#pragma unroll
        for (int j = 0; j < 16; ++j) {
            const float2 v = buf1[swz(sigma1(aBase + j))];
            const float p = v.x * v.x + v.y * v.y;
            S += p;
            z8  += (j & 8) ? -p : p;
            z9  += (j & 4) ? -p : p;
            z10 += (j & 2) ? -p : p;
            z11 += (j & 1) ? -p : p;
        }
        float zq[12];
#pragma unroll
        for (int q = 0; q < 8; ++q)
            zq[q] = ((tid >> (7 - q)) & 1) ? -S : S;
        zq[8] = z8; zq[9] = z9; zq[10] = z10; zq[11] = z11;

        const int lane = tid & 63, wv = tid >> 6;
#pragma unroll
        for (int q = 0; q < 12; ++q) {
            float v = zq[q];
#pragma unroll
            for (int off = 32; off > 0; off >>= 1) v += __shfl_down(v, off);
            if (lane == 0) zredw[wv * 12 + q] = v;
        }
        __syncthreads();   // S5

        // ---- Linear head + activation -> gact; one release-add per WG ----
        if (tid < 4) {
            float acc = bsel[tid];
#pragma unroll
            for (int q = 0; q < 12; ++q) {
                const float zs = zredw[q] + zredw[12 + q] + zredw[24 + q] + zredw[36 + q];
                acc += Wsel[tid * 12 + q] * zs;
            }
            const float act = (g == 2) ? ftanh(acc) : fsigm(acc);
            __hip_atomic_store(&gact[(t & 1) * 1024 + g * 256 + b * 4 + tid], act,
                               __ATOMIC_RELAXED, AGENT);
        }
        if (tid == 0)   // release drains the wave's prior stores (lanes 0..3)
            __hip_atomic_fetch_add(&ctr[b * 16 + t], 1u, __ATOMIC_RELEASE, AGENT);
    }

    // ==== Finalize: consume step-15 activations ====
    if (tid == 64) {
        while (__hip_atomic_load(&ctr[b * 16 + 15], __ATOMIC_RELAXED, AGENT) < 4u)
            __builtin_amdgcn_s_sleep(2);
        __threadfence();
    }
    __syncthreads();
    if (g == 0 && tid < 4) {
        float* ga = gact + 1024 + b * 4;                // slot 15&1 = 1
        const float f_ = __hip_atomic_load(ga + tid,       __ATOMIC_RELAXED, AGENT);
        const float i_ = __hip_atomic_load(ga + 256 + tid, __ATOMIC_RELAXED, AGENT);
        const float g_ = __hip_atomic_load(ga + 512 + tid, __ATOMIC_RELAXED, AGENT);
        const float o_ = __hip_atomic_load(ga + 768 + tid, __ATOMIC_RELAXED, AGENT);
        const float cn = f_ * c4[tid] + i_ * g_;
        const float hn = o_ * ftanh(cn);
        out[3840 + b * 4 + tid] = hn;   // outputs[15]
        out[4096 + b * 4 + tid] = hn;   // hx
        out[4352 + b * 4 + tid] = cn;   // cx
    }
}

extern "C" void kernel_launch(void* const* d_in, const int* in_sizes, int n_in,
                              void* d_out, int out_size, void* d_ws, size_t ws_size,
                              hipStream_t stream) {
    (void)in_sizes; (void)n_in; (void)out_size; (void)ws_size;
    const float* inputs = (const float*)d_in[0];
    const float* wf = (const float*)d_in[1];
    const float* wi = (const float*)d_in[2];
    const float* wu = (const float*)d_in[3];
    const float* wo = (const float*)d_in[4];
    const float* fW = (const float*)d_in[5];
    const float* fb = (const float*)d_in[6];
    const float* iW = (const float*)d_in[7];
    const float* ib = (const float*)d_in[8];
    const float* uW = (const float*)d_in[9];
    const float* ub = (const float*)d_in[10];
    const float* oW = (const float*)d_in[11];
    const float* ob = (const float*)d_in[12];
    float* out = (float*)d_out;
    unsigned* ctr = (unsigned*)d_ws;                 // [64][16] uints (64B/sample)
    float* gact = (float*)d_ws + 1024;               // [2][4][64][4] floats

    hipMemsetAsync(ctr, 0, 1024 * sizeof(unsigned), stream);

    void* args[] = { (void*)&inputs, (void*)&wf, (void*)&wi, (void*)&wu, (void*)&wo,
                     (void*)&fW, (void*)&fb, (void*)&iW, (void*)&ib,
                     (void*)&uW, (void*)&ub, (void*)&oW, (void*)&ob,
                     (void*)&gact, (void*)&ctr, (void*)&out };
    hipError_t err = hipLaunchCooperativeKernel((const void*)qlstm_fused,
                                                dim3(256), dim3(256),
                                                args, 0, stream);
    if (err != hipSuccess) {
        // Fallback: plain launch. 256 WGs (1/CU) co-resident on the idle
        // 256-CU device, so the group rendezvous still works.
        qlstm_fused<<<dim3(256), dim3(256), 0, stream>>>(
            inputs, wf, wi, wu, wo, fW, fb, iW, ib, uW, ub, oW, ob,
            gact, ctr, out);
    }
}